// Round 1
// baseline (1247.845 us; speedup 1.0000x reference)
//
#include <hip/hip_runtime.h>
#include <hip/hip_bf16.h>

#define D_MODEL 1024
#define HDIM    4096
#define NE      8

typedef __attribute__((ext_vector_type(8))) short short8;
typedef __attribute__((ext_vector_type(4))) float f32x4;
typedef __attribute__((ext_vector_type(2))) __bf16 bf16x2;
typedef __attribute__((ext_vector_type(4))) unsigned int uint4v;

__device__ inline unsigned pk2(float a, float b) {
  bf16x2 v; v[0] = (__bf16)a; v[1] = (__bf16)b;
  return __builtin_bit_cast(unsigned, v);
}
__device__ inline unsigned short f2bf(float a) {
  __bf16 v = (__bf16)a;
  return __builtin_bit_cast(unsigned short, v);
}

// ---------------- gating: one block per token ----------------
__global__ __launch_bounds__(256) void gate_kernel(
    const float* __restrict__ x, const float* __restrict__ gw,
    int* __restrict__ counts, int* __restrict__ tk_e, float* __restrict__ tk_g)
{
  const int t = blockIdx.x;
  const int tid = threadIdx.x;
  const float4 xv = ((const float4*)(x + (size_t)t * D_MODEL))[tid];
  float part[NE];
#pragma unroll
  for (int e = 0; e < NE; ++e) {
    const float4 gv = ((const float4*)(gw + e * D_MODEL))[tid];
    part[e] = xv.x * gv.x + xv.y * gv.y + xv.z * gv.z + xv.w * gv.w;
  }
#pragma unroll
  for (int off = 32; off > 0; off >>= 1)
#pragma unroll
    for (int e = 0; e < NE; ++e) part[e] += __shfl_down(part[e], off, 64);
  __shared__ float red[4][NE];
  const int wid = tid >> 6, lane = tid & 63;
  if (lane == 0)
    for (int e = 0; e < NE; ++e) red[wid][e] = part[e];
  __syncthreads();
  if (tid == 0) {
    float lg[NE];
    for (int e = 0; e < NE; ++e) lg[e] = red[0][e] + red[1][e] + red[2][e] + red[3][e];
    int e0 = 0;
    for (int e = 1; e < NE; ++e) if (lg[e] > lg[e0]) e0 = e;
    int e1 = (e0 == 0) ? 1 : 0;
    for (int e = 0; e < NE; ++e) { if (e == e0) continue; if (lg[e] > lg[e1]) e1 = e; }
    const float v0 = lg[e0], v1 = lg[e1];
    const float g0 = 1.0f / (1.0f + expf(v1 - v0));
    tk_e[2*t] = e0; tk_e[2*t+1] = e1;
    tk_g[2*t] = g0; tk_g[2*t+1] = 1.0f - g0;
    atomicAdd(&counts[e0], 1);
    atomicAdd(&counts[e1], 1);
  }
}

__global__ void prefix_kernel(const int* __restrict__ counts,
                              int* __restrict__ cursor, int* __restrict__ offsets) {
  if (threadIdx.x == 0) {
    int s = 0;
    for (int e = 0; e < NE; ++e) { offsets[e] = s; s += counts[e]; cursor[e] = 0; }
  }
}

__global__ __launch_bounds__(256) void place_kernel(
    const int* __restrict__ tk_e, const float* __restrict__ tk_g,
    const int* __restrict__ offsets, int* __restrict__ cursor,
    int* __restrict__ token_of, float* __restrict__ gate_of, int T)
{
  const int t = blockIdx.x * 256 + threadIdx.x;
  if (t >= T) return;
  for (int k = 0; k < 2; ++k) {
    const int e = tk_e[2*t + k];
    const int pos = offsets[e] + atomicAdd(&cursor[e], 1);
    token_of[pos] = t;
    gate_of[pos] = tk_g[2*t + k];
  }
}

// ---------------- GEMM1: h[p,f] = relu( x[tok(p),:] . w1[e][f,:] ) ----------------
__global__ __launch_bounds__(256) void gemm1_kernel(
    const float* __restrict__ x, const float* __restrict__ w1,
    const int* __restrict__ counts, const int* __restrict__ offsets,
    const int* __restrict__ token_of, unsigned short* __restrict__ h)
{
  const int e = blockIdx.y;
  const int ne = counts[e];
  const int zt = blockIdx.z;
  if (zt * 128 >= ne) return;
  const int off = offsets[e];
  const int p0 = off + zt * 128;
  const int pend = off + ne;
  const int f0 = blockIdx.x * 128;
  const float* __restrict__ w1e = w1 + (size_t)e * ((size_t)HDIM * D_MODEL);

  __shared__ __align__(16) short As[128][40];
  __shared__ __align__(16) short Bs[128][40];

  const int tid = threadIdx.x;
  const int r = tid >> 1, ch = tid & 1;
  const int p = p0 + r;
  const int pr = (p < pend) ? p : p0;
  const int tok = token_of[pr];
  const float* aptr = x + (size_t)tok * D_MODEL + ch * 16;
  const float* bptr = w1e + (size_t)(f0 + r) * D_MODEL + ch * 16;

  const int lane = tid & 63, wid = tid >> 6;
  const int wm = (wid & 1) * 64, wn = (wid >> 1) * 64;
  const int lr = lane & 15, lq = lane >> 4;

  f32x4 acc[4][4];
#pragma unroll
  for (int i = 0; i < 4; ++i)
#pragma unroll
    for (int j = 0; j < 4; ++j) acc[i][j] = (f32x4){0.f, 0.f, 0.f, 0.f};

  for (int kk = 0; kk < D_MODEL; kk += 32) {
    const float4 a0 = *(const float4*)(aptr + kk);
    const float4 a1 = *(const float4*)(aptr + kk + 4);
    const float4 a2 = *(const float4*)(aptr + kk + 8);
    const float4 a3 = *(const float4*)(aptr + kk + 12);
    const float4 b0 = *(const float4*)(bptr + kk);
    const float4 b1 = *(const float4*)(bptr + kk + 4);
    const float4 b2 = *(const float4*)(bptr + kk + 8);
    const float4 b3 = *(const float4*)(bptr + kk + 12);
    __syncthreads();
    uint4v wa0 = {pk2(a0.x,a0.y), pk2(a0.z,a0.w), pk2(a1.x,a1.y), pk2(a1.z,a1.w)};
    uint4v wa1 = {pk2(a2.x,a2.y), pk2(a2.z,a2.w), pk2(a3.x,a3.y), pk2(a3.z,a3.w)};
    uint4v wb0 = {pk2(b0.x,b0.y), pk2(b0.z,b0.w), pk2(b1.x,b1.y), pk2(b1.z,b1.w)};
    uint4v wb1 = {pk2(b2.x,b2.y), pk2(b2.z,b2.w), pk2(b3.x,b3.y), pk2(b3.z,b3.w)};
    *(uint4v*)&As[r][ch*16]     = wa0;
    *(uint4v*)&As[r][ch*16 + 8] = wa1;
    *(uint4v*)&Bs[r][ch*16]     = wb0;
    *(uint4v*)&Bs[r][ch*16 + 8] = wb1;
    __syncthreads();
    short8 af[4], bf8[4];
#pragma unroll
    for (int i = 0; i < 4; ++i) af[i]  = *(const short8*)&As[wm + i*16 + lr][lq*8];
#pragma unroll
    for (int j = 0; j < 4; ++j) bf8[j] = *(const short8*)&Bs[wn + j*16 + lr][lq*8];
#pragma unroll
    for (int i = 0; i < 4; ++i)
#pragma unroll
      for (int j = 0; j < 4; ++j)
        acc[i][j] = __builtin_amdgcn_mfma_f32_16x16x32_bf16(af[i], bf8[j], acc[i][j], 0, 0, 0);
  }

#pragma unroll
  for (int i = 0; i < 4; ++i) {
#pragma unroll
    for (int g = 0; g < 4; ++g) {
      const int m = wm + i*16 + lq*4 + g;
      const int pp = p0 + m;
      if (pp < pend) {
        unsigned short* hrow = h + (size_t)pp * HDIM + f0 + wn + lr;
#pragma unroll
        for (int j = 0; j < 4; ++j) {
          float v = acc[i][j][g];
          v = v > 0.f ? v : 0.f;
          hrow[j*16] = f2bf(v);
        }
      }
    }
  }
}

// ---------------- GEMM2: out[tok(p),d] += gate(p) * h[p,:] . w2[e][d,:] ----------------
__global__ __launch_bounds__(256) void gemm2_kernel(
    const unsigned short* __restrict__ h, const float* __restrict__ w2,
    const int* __restrict__ counts, const int* __restrict__ offsets,
    const int* __restrict__ token_of, const float* __restrict__ gate_of,
    float* __restrict__ out)
{
  const int e = blockIdx.y;
  const int ne = counts[e];
  const int zt = blockIdx.z;
  if (zt * 128 >= ne) return;
  const int off = offsets[e];
  const int p0 = off + zt * 128;
  const int pend = off + ne;
  const int d0 = blockIdx.x * 128;
  const float* __restrict__ w2e = w2 + (size_t)e * ((size_t)D_MODEL * HDIM);

  __shared__ __align__(16) short As[128][40];
  __shared__ __align__(16) short Bs[128][40];

  const int tid = threadIdx.x;
  const int r = tid >> 1, ch = tid & 1;
  const int p = p0 + r;
  const int pr = (p < pend) ? p : p0;
  const unsigned short* aptr = h + (size_t)pr * HDIM + ch * 16;
  const float* bptr = w2e + (size_t)(d0 + r) * HDIM + ch * 16;

  const int lane = tid & 63, wid = tid >> 6;
  const int wm = (wid & 1) * 64, wn = (wid >> 1) * 64;
  const int lr = lane & 15, lq = lane >> 4;

  f32x4 acc[4][4];
#pragma unroll
  for (int i = 0; i < 4; ++i)
#pragma unroll
    for (int j = 0; j < 4; ++j) acc[i][j] = (f32x4){0.f, 0.f, 0.f, 0.f};

  for (int kk = 0; kk < HDIM; kk += 32) {
    const short8 av0 = *(const short8*)(aptr + kk);
    const short8 av1 = *(const short8*)(aptr + kk + 8);
    const float4 b0 = *(const float4*)(bptr + kk);
    const float4 b1 = *(const float4*)(bptr + kk + 4);
    const float4 b2 = *(const float4*)(bptr + kk + 8);
    const float4 b3 = *(const float4*)(bptr + kk + 12);
    __syncthreads();
    *(short8*)&As[r][ch*16]     = av0;
    *(short8*)&As[r][ch*16 + 8] = av1;
    uint4v wb0 = {pk2(b0.x,b0.y), pk2(b0.z,b0.w), pk2(b1.x,b1.y), pk2(b1.z,b1.w)};
    uint4v wb1 = {pk2(b2.x,b2.y), pk2(b2.z,b2.w), pk2(b3.x,b3.y), pk2(b3.z,b3.w)};
    *(uint4v*)&Bs[r][ch*16]     = wb0;
    *(uint4v*)&Bs[r][ch*16 + 8] = wb1;
    __syncthreads();
    short8 af[4], bf8[4];
#pragma unroll
    for (int i = 0; i < 4; ++i) af[i]  = *(const short8*)&As[wm + i*16 + lr][lq*8];
#pragma unroll
    for (int j = 0; j < 4; ++j) bf8[j] = *(const short8*)&Bs[wn + j*16 + lr][lq*8];
#pragma unroll
    for (int i = 0; i < 4; ++i)
#pragma unroll
      for (int j = 0; j < 4; ++j)
        acc[i][j] = __builtin_amdgcn_mfma_f32_16x16x32_bf16(af[i], bf8[j], acc[i][j], 0, 0, 0);
  }

#pragma unroll
  for (int i = 0; i < 4; ++i) {
#pragma unroll
    for (int g = 0; g < 4; ++g) {
      const int m = wm + i*16 + lq*4 + g;
      const int pp = p0 + m;
      if (pp < pend) {
        const int tok = token_of[pp];
        const float gv = gate_of[pp];
        float* orow = out + (size_t)tok * D_MODEL + d0 + wn + lr;
#pragma unroll
        for (int j = 0; j < 4; ++j)
          atomicAdd(&orow[j*16], gv * acc[i][j][g]);
      }
    }
  }
}

extern "C" void kernel_launch(void* const* d_in, const int* in_sizes, int n_in,
                              void* d_out, int out_size, void* d_ws, size_t ws_size,
                              hipStream_t stream)
{
  const float* x  = (const float*)d_in[0];
  const float* gw = (const float*)d_in[1];
  const float* w1 = (const float*)d_in[2];
  const float* w2 = (const float*)d_in[3];
  float* out = (float*)d_out;
  const int T = in_sizes[0] / D_MODEL;   // 8192 tokens

  char* wsb = (char*)d_ws;
  int*   counts   = (int*)wsb;           // [8]
  int*   cursor   = counts + 8;          // [8]
  int*   offsets  = cursor + 8;          // [8]
  int*   tk_e     = offsets + 8;         // [2T]
  float* tk_g     = (float*)(tk_e + 2*T);      // [2T]
  int*   token_of = (int*)(tk_g + 2*T);        // [2T]
  float* gate_of  = (float*)(token_of + 2*T);  // [2T]
  unsigned short* h = (unsigned short*)(wsb + (1u << 20)); // [2T][HDIM] bf16 = 128 MiB

  hipMemsetAsync(d_ws, 0, 96, stream);
  hipMemsetAsync(d_out, 0, (size_t)out_size * sizeof(float), stream);

  gate_kernel<<<T, 256, 0, stream>>>(x, gw, counts, tk_e, tk_g);
  prefix_kernel<<<1, 64, 0, stream>>>(counts, cursor, offsets);
  place_kernel<<<(T + 255) / 256, 256, 0, stream>>>(tk_e, tk_g, offsets, cursor,
                                                    token_of, gate_of, T);
  const int maxz = (T + 127) / 128;  // worst-case token tiles per expert
  dim3 g1(HDIM / 128, NE, maxz);
  gemm1_kernel<<<g1, 256, 0, stream>>>(x, w1, counts, offsets, token_of, h);
  dim3 g2(D_MODEL / 128, NE, maxz);
  gemm2_kernel<<<g2, 256, 0, stream>>>(h, w2, counts, offsets, token_of, gate_of, out);
}